// Round 19
// baseline (482.311 us; speedup 1.0000x reference)
//
#include <hip/hip_runtime.h>

#define DEVINL __device__ __forceinline__
typedef __attribute__((ext_vector_type(8))) __bf16 bf16x8;
typedef __attribute__((ext_vector_type(4))) __bf16 bf16x4;
typedef __attribute__((ext_vector_type(4))) float f32x4;

#if __has_builtin(__builtin_amdgcn_exp2f)
#define FAST_EXP2(x) __builtin_amdgcn_exp2f(x)
#else
#define FAST_EXP2(x) __expf((x) * 0.6931471805599453f)
#endif

DEVINL void gload16(void* lds, const void* g) {
  __builtin_amdgcn_global_load_lds((const __attribute__((address_space(1))) void*)g,
                                   (__attribute__((address_space(3))) void*)lds, 16, 0, 0);
}

// ---------- f32 -> bf16 convert (vectorized) ----------
__global__ void cvt_bf16_kernel(const float* __restrict__ in, __bf16* __restrict__ out, int n4) {
  int i = blockIdx.x * 256 + threadIdx.x;
  if (i >= n4) return;
  float4 v = reinterpret_cast<const float4*>(in)[i];
  bf16x4 o;
  o.x = (__bf16)v.x; o.y = (__bf16)v.y; o.z = (__bf16)v.z; o.w = (__bf16)v.w;
  reinterpret_cast<bf16x4*>(out)[i] = o;
}

// ---------- pack W^T: three f32 [1024][1024] -> bf16 [3072][1024] (N-major) ----------
__global__ void wt_pack_kernel(const float* __restrict__ Wq, const float* __restrict__ Wk,
                               const float* __restrict__ Wv, __bf16* __restrict__ WT) {
  __shared__ float t[64][65];
  int k0 = blockIdx.x * 64;
  int n0 = blockIdx.y * 64;
  const float* W = (n0 < 1024) ? Wq : (n0 < 2048 ? Wk : Wv);
  int nn0 = n0 & 1023;
  int r = threadIdx.x >> 6, c = threadIdx.x & 63;
#pragma unroll
  for (int i = 0; i < 16; ++i)
    t[r + i*4][c] = W[(size_t)(k0 + r + i*4) * 1024 + nn0 + c];
  __syncthreads();
#pragma unroll
  for (int i = 0; i < 16; ++i) {
    int row = r + i*4;
    WT[(size_t)(n0 + row) * 1024 + k0 + c] = (__bf16)t[c][row];
  }
}

// ---------- GEMM: C[8192,3072] = A[8192,1024] @ WT^T + bias, bf16 ----------
// BK=32 experiment (FIXED coverage): 128x128 tile, 4 waves, dbuf LDS 32KB ->
// 4 blocks/CU (16 waves/CU), counted vmcnt(4), chunk-XOR swizzle c^((row>>1)&3)
// (2-way banks = free), T5 setprio. Each STAGE: 2 A-chunks + 2 B-chunks per thread
// = full 512-chunk coverage per tile (round-18 bug: only 256 loaded).
// Fused Vt epilogue: V cols (>=2048) written transposed to Vt[b,h][d][s].
__global__ __launch_bounds__(256) void gemm_qkv_kernel(
    const __bf16* __restrict__ A, const __bf16* __restrict__ WT,
    const float* __restrict__ bq, const float* __restrict__ bk, const float* __restrict__ bv,
    __bf16* __restrict__ C, __bf16* __restrict__ Vt, int hcnt, int ldD) {
  constexpr int N_ = 3072, K_ = 1024;
  // per buffer: A[128][32] (8KB) + B[128][32] (8KB); two buffers = 32KB
  __shared__ __align__(16) __bf16 lds[2][(128 + 128) * 32];
  int tid = threadIdx.x;
  int lane = tid & 63;
  int wave = tid >> 6;
  int l15 = lane & 15, l4 = lane >> 4;
  int wr = wave >> 1, wc = wave & 1;
  int n0 = blockIdx.x * 128, m0 = blockIdx.y * 128;

  f32x4 acc[4][4] = {};

  const char* Abase = (const char*)(A  + (size_t)m0 * K_);
  const char* Bbase = (const char*)(WT + (size_t)n0 * K_);

  // stage K-tile kt (BK=32): 2 A-chunks + 2 B-chunks per thread (16B each), 512 chunks total
  auto STAGE = [&](int buf, int kt) {
    char* Al = (char*)lds[buf];
    char* Bl = (char*)(lds[buf] + 128 * 32);
#pragma unroll
    for (int i = 0; i < 2; ++i) {
      int c = i * 256 + tid;
      int r = c >> 2, cc = c & 3, g = cc ^ ((r >> 1) & 3);   // pre-swizzled global chunk
      gload16(Al + (size_t)(c & ~63) * 16,
              Abase + (size_t)r * (K_ * 2) + kt * 64 + g * 16);
      gload16(Bl + (size_t)(c & ~63) * 16,
              Bbase + (size_t)r * (K_ * 2) + kt * 64 + g * 16);
    }
  };

  int cur = 0;
  STAGE(0, 0);
  for (int kt = 0; kt < 32; ++kt) {
    if (kt < 31) {
      STAGE(cur ^ 1, kt + 1);
      asm volatile("s_waitcnt vmcnt(4)" ::: "memory");  // own tile-kt loads done; 4 in flight
    } else {
      asm volatile("s_waitcnt vmcnt(0)" ::: "memory");
    }
    __builtin_amdgcn_s_barrier();
    const char* Al = (const char*)lds[cur];
    const char* Bl = (const char*)(lds[cur] + 128 * 32);
    bf16x8 af[4], bfr[4];
#pragma unroll
    for (int m = 0; m < 4; ++m) {
      int row = wr * 64 + m * 16 + l15;
      af[m] = *(const bf16x8*)(Al + ((size_t)row * 4 + (l4 ^ ((row >> 1) & 3))) * 16);
    }
#pragma unroll
    for (int n = 0; n < 4; ++n) {
      int row = wc * 64 + n * 16 + l15;
      bfr[n] = *(const bf16x8*)(Bl + ((size_t)row * 4 + (l4 ^ ((row >> 1) & 3))) * 16);
    }
    __builtin_amdgcn_s_setprio(1);
#pragma unroll
    for (int m = 0; m < 4; ++m)
#pragma unroll
      for (int n = 0; n < 4; ++n)
        acc[m][n] = __builtin_amdgcn_mfma_f32_16x16x32_bf16(af[m], bfr[n], acc[m][n], 0, 0, 0);
    __builtin_amdgcn_s_setprio(0);
    __builtin_amdgcn_s_barrier();
    cur ^= 1;
  }

#pragma unroll
  for (int n = 0; n < 4; ++n) {
    int col = n0 + wc * 64 + n * 16 + l15;
    if (col < 2048) {
      const float* bias = (col < 1024) ? bq : bk;
      float bv_ = bias[col & 1023];
#pragma unroll
      for (int m = 0; m < 4; ++m) {
        int rowb = m0 + wr * 64 + m * 16 + l4 * 4;
#pragma unroll
        for (int r = 0; r < 4; ++r)
          C[(size_t)(rowb + r) * N_ + col] = (__bf16)(acc[m][n][r] + bv_);
      }
    } else {
      int vcol = col - 2048;
      int h = vcol >> ldD, dd = vcol & ((1 << ldD) - 1);
      float bv_ = bv[vcol];
#pragma unroll
      for (int m = 0; m < 4; ++m) {
        int rowb = m0 + wr * 64 + m * 16 + l4 * 4;
        int b = rowb >> 10, s = rowb & 1023;
        bf16x4 pk;
#pragma unroll
        for (int r = 0; r < 4; ++r) pk[r] = (__bf16)(acc[m][n][r] + bv_);
        *reinterpret_cast<bf16x4*>(Vt + (((size_t)(b*hcnt + h) << ldD) + dd)*1024 + s) = pk;
      }
    }
  }
}

// ---------- attention + FUSED masked mean-pool partial ----------
// flash-style, no-max softmax, XCD-grouped blocks, cross-phase staging overlap.
template<int D, int WQ, int HCNT>
__global__ __launch_bounds__(256) void attn_kernel(
    const __bf16* __restrict__ QKV, const __bf16* __restrict__ Vt,
    const int* __restrict__ mask, float* __restrict__ pp) {
  constexpr int QT  = 4*WQ;      // q rows per block
  constexpr int QB  = 1024/QT;   // q-blocks per (b,h)
  constexpr int MT  = WQ/16;
  constexpr int KC  = D/32;
  constexpr int NT2 = D/16;
  constexpr int CPR = D/8;
  __shared__ __align__(16) __bf16 smem[64*D + D*64 + 4*WQ*72];
  __bf16* Kl = smem;
  __bf16* Vl = smem + 64*D;
  __bf16* Pl = smem + 128*D;

  int tid = threadIdx.x;
  int lane = tid & 63, wave = tid >> 6;
  int l15 = lane & 15, l4 = lane >> 4;
  // XCD-grouped decode: d%8 = XCD; all QB q-blocks of one (b,h) share an XCD.
  int d = blockIdx.x;
  int xcd = d & 7, j = d >> 3;
  int qb = j % QB, g = j / QB;
  int p = g*8 + xcd;                       // (b,h) pair index
  int h = p % HCNT, b = p / HCNT;
  int q0 = qb * QT;
  // exp(s*scale) = exp2(s*scale*log2e); FAST_EXP2 -> v_exp_f32
  const float scale2 = ((D == 128) ? 0.08838834764831845f : 0.0625f) * 1.4426950408889634f;

  // stage Q tile [QT][D], swizzled source -> linear LDS
  {
    const char* qbase = (const char*)(QKV + (size_t)(b*1024 + q0)*3072 + (size_t)h*D);
    for (int c0 = 0; c0 < QT*D/8; c0 += 256) {
      int c = c0 + tid;
      int row = c / CPR, cc = c % CPR;
      gload16((char*)smem + (c0 + (tid & ~63))*16,
              qbase + (size_t)row*6144 + ((cc ^ (row & 7))*16));
    }
  }
  __syncthreads();
  bf16x8 qf[MT][KC];
#pragma unroll
  for (int m = 0; m < MT; ++m)
#pragma unroll
    for (int kc = 0; kc < KC; ++kc) {
      int row = wave*WQ + m*16 + l15;
      int boff = ((kc*32 + l4*8)*2) ^ ((row & 7) << 4);
      qf[m][kc] = *(const bf16x8*)((const char*)smem + (size_t)row*(D*2) + boff);
    }
  __syncthreads();

  f32x4 ao[MT][NT2] = {};
  float dsum[MT][4] = {};

  const char* kbase = (const char*)(QKV + (size_t)(b*1024)*3072 + 1024 + (size_t)h*D);
  const char* vbase = (const char*)(Vt + (size_t)(b*HCNT + h)*D*1024);

  auto STAGE_K = [&](int t) {
    for (int c0 = 0; c0 < 8*D; c0 += 256) {
      int c = c0 + tid;
      int row = c / CPR, cc = c % CPR;
      gload16((char*)Kl + (c0 + (tid & ~63))*16,
              kbase + (size_t)(t*64 + row)*6144 + ((cc ^ (row & 7))*16));
    }
  };
  auto STAGE_V = [&](int t) {
    for (int c0 = 0; c0 < 8*D; c0 += 256) {
      int c = c0 + tid;
      int row = c >> 3, cc = c & 7;
      gload16((char*)Vl + (c0 + (tid & ~63))*16,
              vbase + (size_t)row*2048 + t*128 + ((cc ^ (row & 7))*16));
    }
  };

  STAGE_K(0);
  for (int t = 0; t < 16; ++t) {
    __syncthreads();                 // K(t) landed; Vl free
    STAGE_V(t);                      // V loads fly under QK^T
    float mv[4];
#pragma unroll
    for (int n = 0; n < 4; ++n)
      mv[n] = (float)mask[b*1024 + t*64 + n*16 + l15];

    // QK^T -> exp -> P
#pragma unroll
    for (int n = 0; n < 4; ++n) {
      f32x4 s[MT] = {};
#pragma unroll
      for (int kc = 0; kc < KC; ++kc) {
        int krow = n*16 + l15;
        int boff = ((kc*32 + l4*8)*2) ^ ((krow & 7) << 4);
        bf16x8 kf = *(const bf16x8*)((const char*)Kl + (size_t)krow*(D*2) + boff);
#pragma unroll
        for (int m = 0; m < MT; ++m)
          s[m] = __builtin_amdgcn_mfma_f32_16x16x32_bf16(qf[m][kc], kf, s[m], 0, 0, 0);
      }
#pragma unroll
      for (int m = 0; m < MT; ++m)
#pragma unroll
        for (int r = 0; r < 4; ++r) {
          float pf_ = FAST_EXP2(s[m][r] * scale2) * mv[n];
          __bf16 pb = (__bf16)pf_;
          dsum[m][r] += (float)pb;   // num/denom consistently rounded
          Pl[(size_t)(wave*WQ + m*16 + l4*4 + r)*72 + n*16 + l15] = pb;
        }
    }
    __syncthreads();                 // V(t) landed; Kl free
    if (t < 15) STAGE_K(t + 1);      // next-K loads fly under PV

    // PV
    bf16x8 pfr[MT][2];
#pragma unroll
    for (int m = 0; m < MT; ++m)
#pragma unroll
      for (int kk = 0; kk < 2; ++kk)
        pfr[m][kk] = *(const bf16x8*)(Pl + (size_t)(wave*WQ + m*16 + l15)*72 + kk*32 + l4*8);
#pragma unroll
    for (int n2 = 0; n2 < NT2; ++n2) {
      bf16x8 vf[2];
#pragma unroll
      for (int kk = 0; kk < 2; ++kk) {
        int vrow = n2*16 + l15;
        int boff = ((kk*32 + l4*8)*2) ^ ((vrow & 7) << 4);
        vf[kk] = *(const bf16x8*)((const char*)Vl + (size_t)vrow*128 + boff);
      }
#pragma unroll
      for (int m = 0; m < MT; ++m)
#pragma unroll
        for (int kk = 0; kk < 2; ++kk)
          ao[m][n2] = __builtin_amdgcn_mfma_f32_16x16x32_bf16(pfr[m][kk], vf[kk], ao[m][n2], 0, 0, 0);
    }
  }

  // softmax denominators (row sums over 16 key-lanes)
  float inv[MT][4];
#pragma unroll
  for (int m = 0; m < MT; ++m)
#pragma unroll
    for (int r = 0; r < 4; ++r) {
      float v = dsum[m][r];
      v += __shfl_xor(v, 1, 64);
      v += __shfl_xor(v, 2, 64);
      v += __shfl_xor(v, 4, 64);
      v += __shfl_xor(v, 8, 64);
      inv[m][r] = 1.0f / v;
    }

  // fused masked-pool partial
  float mrow[MT][4];
#pragma unroll
  for (int m = 0; m < MT; ++m)
#pragma unroll
    for (int r = 0; r < 4; ++r)
      mrow[m][r] = (float)mask[b*1024 + q0 + wave*WQ + m*16 + l4*4 + r];

  float* fl = (float*)smem;          // [4 waves][D] floats, reuses LDS
  __syncthreads();
#pragma unroll
  for (int n2 = 0; n2 < NT2; ++n2) {
    float pa = 0.f;
#pragma unroll
    for (int m = 0; m < MT; ++m)
#pragma unroll
      for (int r = 0; r < 4; ++r)
        pa += mrow[m][r] * ao[m][n2][r] * inv[m][r];
    pa += __shfl_xor(pa, 16, 64);
    pa += __shfl_xor(pa, 32, 64);
    if (l4 == 0) fl[wave*D + n2*16 + l15] = pa;
  }
  __syncthreads();
  for (int c = tid; c < D; c += 256) {
    float s_ = fl[c] + fl[D + c] + fl[2*D + c] + fl[3*D + c];
    pp[((size_t)(b*QB + qb))*1024 + h*D + c] = s_;
  }
}

// ---------- mask denominator ----------
__global__ void denom_kernel(const int* __restrict__ mask, float* __restrict__ denom) {
  int b = blockIdx.x, t = threadIdx.x;
  int acc = 0;
  for (int s = t; s < 1024; s += 256) acc += mask[b*1024 + s];
  for (int o = 32; o; o >>= 1) acc += __shfl_down(acc, o, 64);
  __shared__ int red[4];
  if ((t & 63) == 0) red[t >> 6] = acc;
  __syncthreads();
  if (t == 0) denom[b] = (float)(red[0] + red[1] + red[2] + red[3]);
}

// ---------- pool reduce: sum QB q-block partials, divide by mask denom ----------
__global__ void pool_reduce_kernel(const float* __restrict__ part, const float* __restrict__ denom,
                                   float* __restrict__ out, int QB) {
  int i = blockIdx.x*256 + threadIdx.x;
  int b = i >> 10, c = i & 1023;
  float a = 0.f;
  for (int qb = 0; qb < QB; ++qb) a += part[((size_t)(b*QB + qb))*1024 + c];
  out[i] = a / denom[b];
}

// ---------- O-projection, k-split stage 1 ----------
__global__ void oproj_partial_kernel(const float* __restrict__ pooled,
    const float* __restrict__ W0, const float* __restrict__ W1, const float* __restrict__ W2,
    float* __restrict__ part) {
  int ai = blockIdx.z;
  const float* W = (ai == 0) ? W0 : (ai == 1 ? W1 : W2);
  int ks = blockIdx.y, k0 = ks*128;
  __shared__ float xl[8*128];
  const float* P = pooled + ai*8192;
  for (int i = threadIdx.x; i < 8*128; i += 256) {
    int b = i >> 7, kk = i & 127;
    xl[i] = P[b*1024 + k0 + kk];
  }
  __syncthreads();
  int n = blockIdx.x*256 + threadIdx.x;
  float acc[8] = {};
  for (int kk = 0; kk < 128; ++kk) {
    float w = W[(size_t)(k0+kk)*1024 + n];
#pragma unroll
    for (int b = 0; b < 8; ++b) acc[b] += xl[b*128 + kk] * w;
  }
#pragma unroll
  for (int b = 0; b < 8; ++b) part[(((size_t)ai*8 + ks)*8 + b)*1024 + n] = acc[b];
}

// ---------- O-projection, stage 2 ----------
__global__ void oproj_reduce_kernel(const float* __restrict__ part,
    const float* __restrict__ b0, const float* __restrict__ b1, const float* __restrict__ b2,
    float* __restrict__ fused) {
  int i = blockIdx.x*256 + threadIdx.x;
  int ai = i >> 13, rem = i & 8191;
  int b = rem >> 10, n = rem & 1023;
  const float* bb = (ai == 0) ? b0 : (ai == 1 ? b1 : b2);
  float a = bb[n];
#pragma unroll
  for (int ks = 0; ks < 8; ++ks) a += part[(((size_t)ai*8 + ks)*8 + b)*1024 + n];
  fused[b*3072 + ai*1024 + n] = a;
}

// ---------- small FC: k-split partials, then reduce ----------
__global__ void fc_partial_kernel(const float* __restrict__ X, const float* __restrict__ W,
                                  float* __restrict__ part, int Kin, int Nout, int kchunk) {
  extern __shared__ float xl[];
  int ks = blockIdx.y, k0 = ks*kchunk;
  for (int i = threadIdx.x; i < 8*kchunk; i += 256) {
    int b = i / kchunk, kk = i - b*kchunk;
    xl[i] = X[b*Kin + k0 + kk];
  }
  __syncthreads();
  int n = blockIdx.x*256 + threadIdx.x;
  float acc[8] = {};
  for (int kk = 0; kk < kchunk; ++kk) {
    float w = W[(size_t)(k0+kk)*Nout + n];
#pragma unroll
    for (int b = 0; b < 8; ++b) acc[b] += xl[b*kchunk + kk] * w;
  }
#pragma unroll
  for (int b = 0; b < 8; ++b) part[((size_t)ks*8 + b)*Nout + n] = acc[b];
}

__global__ void fc_reduce_kernel(const float* __restrict__ part, const float* __restrict__ bias,
                                 float* __restrict__ out, int Nout, int KS, int do_relu) {
  int i = blockIdx.x*256 + threadIdx.x;
  int b = i / Nout, n = i - b*Nout;
  float a = bias[n];
  for (int ks = 0; ks < KS; ++ks) a += part[((size_t)ks*8 + b)*Nout + n];
  out[i] = do_relu ? fmaxf(a, 0.f) : a;
}

// ---------- classifier [8,512] @ [512,2] ----------
__global__ void cls_kernel(const float* __restrict__ h2, const float* __restrict__ W,
                           const float* __restrict__ bias, float* __restrict__ out) {
  int t = threadIdx.x;
  int o = t >> 4, sl = t & 15;
  int b = o >> 1, n = o & 1;
  float a = 0.f;
  for (int k = sl; k < 512; k += 16) a += h2[b*512 + k] * W[k*2 + n];
#pragma unroll
  for (int m = 1; m < 16; m <<= 1) a += __shfl_xor(a, m, 64);
  if (sl == 0) out[o] = a + bias[n];
}

extern "C" void kernel_launch(void* const* d_in, const int* in_sizes, int n_in,
                              void* d_out, int out_size, void* d_ws, size_t ws_size,
                              hipStream_t stream) {
  const float* X   = (const float*)d_in[0];
  const int* mask  = (const int*)d_in[1];
  const float* w_[3][8];
  for (int a = 0; a < 3; ++a)
    for (int j = 0; j < 8; ++j)
      w_[a][j] = (const float*)d_in[2 + a*8 + j];
  const float* fus1_w = (const float*)d_in[26];
  const float* fus1_b = (const float*)d_in[27];
  const float* fus2_w = (const float*)d_in[28];
  const float* fus2_b = (const float*)d_in[29];
  const float* cls_w  = (const float*)d_in[30];
  const float* cls_b  = (const float*)d_in[31];

  char* p = (char*)d_ws;
  auto carve = [&](size_t bytes) { char* r = p; p += (bytes + 255) & ~(size_t)255; return r; };
  __bf16* Xb    = (__bf16*)carve((size_t)8192*1024*2);
  __bf16* WTb   = (__bf16*)carve((size_t)3072*1024*2);
  __bf16* QKVb  = (__bf16*)carve((size_t)8192*3072*2);
  __bf16* Vtb   = (__bf16*)carve((size_t)8192*1024*2);
  float* pooledb= (float*)carve(3*8*1024*4);
  float* denomb = (float*)carve(256);
  float* fusedb = (float*)carve(8*3072*4);
  float* partb  = (float*)carve((size_t)24*8*1024*4);
  float* opartb = (float*)carve((size_t)3*8*8*1024*4);
  float* poolpartb = (float*)carve((size_t)8*16*1024*4);
  float* h1b    = (float*)carve(8*1024*4);
  float* h2b    = (float*)carve(8*512*4);
  if ((size_t)(p - (char*)d_ws) > ws_size) return;  // workspace too small: fail loudly

  cvt_bf16_kernel<<<8192, 256, 0, stream>>>(X, Xb, 8192*1024/4);
  denom_kernel<<<8, 256, 0, stream>>>(mask, denomb);

  for (int a = 0; a < 3; ++a) {
    wt_pack_kernel<<<dim3(16,48), 256, 0, stream>>>(w_[a][0], w_[a][2], w_[a][4], WTb);
    if (a == 0) {
      gemm_qkv_kernel<<<dim3(24,64), 256, 0, stream>>>(Xb, WTb, w_[a][1], w_[a][3], w_[a][5],
                                                       QKVb, Vtb, 8, 7);
      attn_kernel<128,32,8><<<512, 256, 0, stream>>>(QKVb, Vtb, mask, poolpartb);
      pool_reduce_kernel<<<32, 256, 0, stream>>>(poolpartb, denomb, pooledb + a*8192, 8);
    } else {
      gemm_qkv_kernel<<<dim3(24,64), 256, 0, stream>>>(Xb, WTb, w_[a][1], w_[a][3], w_[a][5],
                                                       QKVb, Vtb, 4, 8);
      attn_kernel<256,16,4><<<512, 256, 0, stream>>>(QKVb, Vtb, mask, poolpartb);
      pool_reduce_kernel<<<32, 256, 0, stream>>>(poolpartb, denomb, pooledb + a*8192, 16);
    }
  }

  oproj_partial_kernel<<<dim3(4,8,3), 256, 0, stream>>>(pooledb,
      w_[0][6], w_[1][6], w_[2][6], opartb);
  oproj_reduce_kernel<<<96, 256, 0, stream>>>(opartb,
      w_[0][7], w_[1][7], w_[2][7], fusedb);
  fc_partial_kernel<<<dim3(4,24), 256, 8*128*4, stream>>>(fusedb, fus1_w, partb, 3072, 1024, 128);
  fc_reduce_kernel<<<32, 256, 0, stream>>>(partb, fus1_b, h1b, 1024, 24, 1);
  fc_partial_kernel<<<dim3(2,8), 256, 8*128*4, stream>>>(h1b, fus2_w, partb, 1024, 512, 128);
  fc_reduce_kernel<<<16, 256, 0, stream>>>(partb, fus2_b, h2b, 512, 8, 1);
  cls_kernel<<<1, 256, 0, stream>>>(h2b, cls_w, cls_b, (float*)d_out);
}

// Round 21
// 466.908 us; speedup vs baseline: 1.0330x; 1.0330x over previous
//
#include <hip/hip_runtime.h>

#define DEVINL __device__ __forceinline__
typedef __attribute__((ext_vector_type(8))) __bf16 bf16x8;
typedef __attribute__((ext_vector_type(4))) __bf16 bf16x4;
typedef __attribute__((ext_vector_type(4))) float f32x4;

#if __has_builtin(__builtin_amdgcn_exp2f)
#define FAST_EXP2(x) __builtin_amdgcn_exp2f(x)
#else
#define FAST_EXP2(x) __expf((x) * 0.6931471805599453f)
#endif

DEVINL void gload16(void* lds, const void* g) {
  __builtin_amdgcn_global_load_lds((const __attribute__((address_space(1))) void*)g,
                                   (__attribute__((address_space(3))) void*)lds, 16, 0, 0);
}

// ---------- f32 -> bf16 convert (vectorized) ----------
__global__ void cvt_bf16_kernel(const float* __restrict__ in, __bf16* __restrict__ out, int n4) {
  int i = blockIdx.x * 256 + threadIdx.x;
  if (i >= n4) return;
  float4 v = reinterpret_cast<const float4*>(in)[i];
  bf16x4 o;
  o.x = (__bf16)v.x; o.y = (__bf16)v.y; o.z = (__bf16)v.z; o.w = (__bf16)v.w;
  reinterpret_cast<bf16x4*>(out)[i] = o;
}

// ---------- pack W^T: three f32 [1024][1024] -> bf16 [3072][1024] (N-major) ----------
__global__ void wt_pack_kernel(const float* __restrict__ Wq, const float* __restrict__ Wk,
                               const float* __restrict__ Wv, __bf16* __restrict__ WT) {
  __shared__ float t[64][65];
  int k0 = blockIdx.x * 64;
  int n0 = blockIdx.y * 64;
  const float* W = (n0 < 1024) ? Wq : (n0 < 2048 ? Wk : Wv);
  int nn0 = n0 & 1023;
  int r = threadIdx.x >> 6, c = threadIdx.x & 63;
#pragma unroll
  for (int i = 0; i < 16; ++i)
    t[r + i*4][c] = W[(size_t)(k0 + r + i*4) * 1024 + nn0 + c];
  __syncthreads();
#pragma unroll
  for (int i = 0; i < 16; ++i) {
    int row = r + i*4;
    WT[(size_t)(n0 + row) * 1024 + k0 + c] = (__bf16)t[c][row];
  }
}

// ---------- GEMM: C[8192,3072] = A[8192,1024] @ WT^T + bias, bf16 ----------
// MEASURED-BEST structure (ledger: BK64-dbuf=72.2 | 96KB-8w=72.8 | 1buf=77.9 | BK32=80.1):
// 128x128 tile, BK=64, 4 waves, dbuf 64KB (2 blocks/CU), counted vmcnt(8),
// T2 XOR-swizzle (0 conflicts), T5 setprio. Fused Vt epilogue for V columns.
__global__ __launch_bounds__(256) void gemm_qkv_kernel(
    const __bf16* __restrict__ A, const __bf16* __restrict__ WT,
    const float* __restrict__ bq, const float* __restrict__ bk, const float* __restrict__ bv,
    __bf16* __restrict__ C, __bf16* __restrict__ Vt, int hcnt, int ldD) {
  constexpr int N_ = 3072, K_ = 1024;
  __shared__ __align__(16) __bf16 lds[2][(128 + 128) * 64];
  int tid = threadIdx.x;
  int lane = tid & 63;
  int wave = tid >> 6;
  int l15 = lane & 15, l4 = lane >> 4;
  int wr = wave >> 1, wc = wave & 1;
  int n0 = blockIdx.x * 128, m0 = blockIdx.y * 128;

  f32x4 acc[4][4] = {};

  const char* Abase = (const char*)(A  + (size_t)m0 * K_);
  const char* Bbase = (const char*)(WT + (size_t)n0 * K_);

  auto STAGE = [&](int buf, int kt) {
    char* Al = (char*)lds[buf];
    char* Bl = (char*)(lds[buf] + 128 * 64);
#pragma unroll
    for (int i = 0; i < 4; ++i) {
      int c = i * 256 + tid;
      int r = c >> 3, cc = c & 7, g = cc ^ (r & 7);
      gload16(Al + (size_t)(c & ~63) * 16,
              Abase + (size_t)r * (K_ * 2) + kt * 128 + g * 16);
      gload16(Bl + (size_t)(c & ~63) * 16,
              Bbase + (size_t)r * (K_ * 2) + kt * 128 + g * 16);
    }
  };

  int cur = 0;
  STAGE(0, 0);
  for (int kt = 0; kt < 16; ++kt) {
    if (kt < 15) {
      STAGE(cur ^ 1, kt + 1);
      asm volatile("s_waitcnt vmcnt(8)" ::: "memory");
    } else {
      asm volatile("s_waitcnt vmcnt(0)" ::: "memory");
    }
    __builtin_amdgcn_s_barrier();
    const char* Al = (const char*)lds[cur];
    const char* Bl = (const char*)(lds[cur] + 128 * 64);
#pragma unroll
    for (int kk = 0; kk < 2; ++kk) {
      bf16x8 af[4], bfr[4];
      int j = kk * 4 + l4;
#pragma unroll
      for (int m = 0; m < 4; ++m) {
        int row = wr * 64 + m * 16 + l15;
        af[m] = *(const bf16x8*)(Al + ((size_t)row * 8 + (j ^ (row & 7))) * 16);
      }
#pragma unroll
      for (int n = 0; n < 4; ++n) {
        int row = wc * 64 + n * 16 + l15;
        bfr[n] = *(const bf16x8*)(Bl + ((size_t)row * 8 + (j ^ (row & 7))) * 16);
      }
      __builtin_amdgcn_s_setprio(1);
#pragma unroll
      for (int m = 0; m < 4; ++m)
#pragma unroll
        for (int n = 0; n < 4; ++n)
          acc[m][n] = __builtin_amdgcn_mfma_f32_16x16x32_bf16(af[m], bfr[n], acc[m][n], 0, 0, 0);
      __builtin_amdgcn_s_setprio(0);
    }
    __builtin_amdgcn_s_barrier();
    cur ^= 1;
  }

#pragma unroll
  for (int n = 0; n < 4; ++n) {
    int col = n0 + wc * 64 + n * 16 + l15;
    if (col < 2048) {
      const float* bias = (col < 1024) ? bq : bk;
      float bv_ = bias[col & 1023];
#pragma unroll
      for (int m = 0; m < 4; ++m) {
        int rowb = m0 + wr * 64 + m * 16 + l4 * 4;
#pragma unroll
        for (int r = 0; r < 4; ++r)
          C[(size_t)(rowb + r) * N_ + col] = (__bf16)(acc[m][n][r] + bv_);
      }
    } else {
      int vcol = col - 2048;
      int h = vcol >> ldD, dd = vcol & ((1 << ldD) - 1);
      float bv_ = bv[vcol];
#pragma unroll
      for (int m = 0; m < 4; ++m) {
        int rowb = m0 + wr * 64 + m * 16 + l4 * 4;
        int b = rowb >> 10, s = rowb & 1023;
        bf16x4 pk;
#pragma unroll
        for (int r = 0; r < 4; ++r) pk[r] = (__bf16)(acc[m][n][r] + bv_);
        *reinterpret_cast<bf16x4*>(Vt + (((size_t)(b*hcnt + h) << ldD) + dd)*1024 + s) = pk;
      }
    }
  }
}

// ---------- attention + FUSED masked mean-pool partial ----------
// flash-style, no-max softmax, XCD-grouped blocks, cross-phase staging overlap.
// NW = waves per block (D=128: 8 waves -> 16 waves/CU; D=256: 4, LDS-bound).
template<int D, int WQ, int HCNT, int NW>
__global__ __launch_bounds__(NW*64) void attn_kernel(
    const __bf16* __restrict__ QKV, const __bf16* __restrict__ Vt,
    const int* __restrict__ mask, float* __restrict__ pp) {
  constexpr int NT  = NW*64;     // threads
  constexpr int QT  = NW*WQ;     // q rows per block
  constexpr int QB  = 1024/QT;   // q-blocks per (b,h)
  constexpr int MT  = WQ/16;
  constexpr int KC  = D/32;
  constexpr int NT2 = D/16;
  constexpr int CPR = D/8;
  __shared__ __align__(16) __bf16 smem[64*D + D*64 + QT*72];
  __bf16* Kl = smem;
  __bf16* Vl = smem + 64*D;
  __bf16* Pl = smem + 128*D;

  int tid = threadIdx.x;
  int lane = tid & 63, wave = tid >> 6;
  int l15 = lane & 15, l4 = lane >> 4;
  // XCD-grouped decode: d%8 = XCD; all QB q-blocks of one (b,h) share an XCD.
  int d = blockIdx.x;
  int xcd = d & 7, j = d >> 3;
  int qb = j % QB, g = j / QB;
  int p = g*8 + xcd;                       // (b,h) pair index
  int h = p % HCNT, b = p / HCNT;
  int q0 = qb * QT;
  // exp(s*scale) = exp2(s*scale*log2e); FAST_EXP2 -> v_exp_f32
  const float scale2 = ((D == 128) ? 0.08838834764831845f : 0.0625f) * 1.4426950408889634f;

  // stage Q tile [QT][D], swizzled source -> linear LDS
  {
    const char* qbase = (const char*)(QKV + (size_t)(b*1024 + q0)*3072 + (size_t)h*D);
    for (int c0 = 0; c0 < QT*D/8; c0 += NT) {
      int c = c0 + tid;
      int row = c / CPR, cc = c % CPR;
      gload16((char*)smem + (c0 + (tid & ~63))*16,
              qbase + (size_t)row*6144 + ((cc ^ (row & 7))*16));
    }
  }
  __syncthreads();
  bf16x8 qf[MT][KC];
#pragma unroll
  for (int m = 0; m < MT; ++m)
#pragma unroll
    for (int kc = 0; kc < KC; ++kc) {
      int row = wave*WQ + m*16 + l15;
      int boff = ((kc*32 + l4*8)*2) ^ ((row & 7) << 4);
      qf[m][kc] = *(const bf16x8*)((const char*)smem + (size_t)row*(D*2) + boff);
    }
  __syncthreads();

  f32x4 ao[MT][NT2] = {};
  float dsum[MT][4] = {};

  const char* kbase = (const char*)(QKV + (size_t)(b*1024)*3072 + 1024 + (size_t)h*D);
  const char* vbase = (const char*)(Vt + (size_t)(b*HCNT + h)*D*1024);

  auto STAGE_K = [&](int t) {
    for (int c0 = 0; c0 < 8*D; c0 += NT) {
      int c = c0 + tid;
      int row = c / CPR, cc = c % CPR;
      gload16((char*)Kl + (c0 + (tid & ~63))*16,
              kbase + (size_t)(t*64 + row)*6144 + ((cc ^ (row & 7))*16));
    }
  };
  auto STAGE_V = [&](int t) {
    for (int c0 = 0; c0 < 8*D; c0 += NT) {
      int c = c0 + tid;
      int row = c >> 3, cc = c & 7;
      gload16((char*)Vl + (c0 + (tid & ~63))*16,
              vbase + (size_t)row*2048 + t*128 + ((cc ^ (row & 7))*16));
    }
  };

  STAGE_K(0);
  for (int t = 0; t < 16; ++t) {
    __syncthreads();                 // K(t) landed; Vl free
    STAGE_V(t);                      // V loads fly under QK^T
    float mv[4];
#pragma unroll
    for (int n = 0; n < 4; ++n)
      mv[n] = (float)mask[b*1024 + t*64 + n*16 + l15];

    // QK^T -> exp -> P
#pragma unroll
    for (int n = 0; n < 4; ++n) {
      f32x4 s[MT] = {};
#pragma unroll
      for (int kc = 0; kc < KC; ++kc) {
        int krow = n*16 + l15;
        int boff = ((kc*32 + l4*8)*2) ^ ((krow & 7) << 4);
        bf16x8 kf = *(const bf16x8*)((const char*)Kl + (size_t)krow*(D*2) + boff);
#pragma unroll
        for (int m = 0; m < MT; ++m)
          s[m] = __builtin_amdgcn_mfma_f32_16x16x32_bf16(qf[m][kc], kf, s[m], 0, 0, 0);
      }
#pragma unroll
      for (int m = 0; m < MT; ++m)
#pragma unroll
        for (int r = 0; r < 4; ++r) {
          float pf_ = FAST_EXP2(s[m][r] * scale2) * mv[n];
          __bf16 pb = (__bf16)pf_;
          dsum[m][r] += (float)pb;   // num/denom consistently rounded
          Pl[(size_t)(wave*WQ + m*16 + l4*4 + r)*72 + n*16 + l15] = pb;
        }
    }
    __syncthreads();                 // V(t) landed; Kl free
    if (t < 15) STAGE_K(t + 1);      // next-K loads fly under PV

    // PV
    bf16x8 pfr[MT][2];
#pragma unroll
    for (int m = 0; m < MT; ++m)
#pragma unroll
      for (int kk = 0; kk < 2; ++kk)
        pfr[m][kk] = *(const bf16x8*)(Pl + (size_t)(wave*WQ + m*16 + l15)*72 + kk*32 + l4*8);
#pragma unroll
    for (int n2 = 0; n2 < NT2; ++n2) {
      bf16x8 vf[2];
#pragma unroll
      for (int kk = 0; kk < 2; ++kk) {
        int vrow = n2*16 + l15;
        int boff = ((kk*32 + l4*8)*2) ^ ((vrow & 7) << 4);
        vf[kk] = *(const bf16x8*)((const char*)Vl + (size_t)vrow*128 + boff);
      }
#pragma unroll
      for (int m = 0; m < MT; ++m)
#pragma unroll
        for (int kk = 0; kk < 2; ++kk)
          ao[m][n2] = __builtin_amdgcn_mfma_f32_16x16x32_bf16(pfr[m][kk], vf[kk], ao[m][n2], 0, 0, 0);
    }
  }

  // softmax denominators (row sums over 16 key-lanes)
  float inv[MT][4];
#pragma unroll
  for (int m = 0; m < MT; ++m)
#pragma unroll
    for (int r = 0; r < 4; ++r) {
      float v = dsum[m][r];
      v += __shfl_xor(v, 1, 64);
      v += __shfl_xor(v, 2, 64);
      v += __shfl_xor(v, 4, 64);
      v += __shfl_xor(v, 8, 64);
      inv[m][r] = 1.0f / v;
    }

  // fused masked-pool partial
  float mrow[MT][4];
#pragma unroll
  for (int m = 0; m < MT; ++m)
#pragma unroll
    for (int r = 0; r < 4; ++r)
      mrow[m][r] = (float)mask[b*1024 + q0 + wave*WQ + m*16 + l4*4 + r];

  float* fl = (float*)smem;          // [NW waves][D] floats, reuses LDS
  __syncthreads();
#pragma unroll
  for (int n2 = 0; n2 < NT2; ++n2) {
    float pa = 0.f;
#pragma unroll
    for (int m = 0; m < MT; ++m)
#pragma unroll
      for (int r = 0; r < 4; ++r)
        pa += mrow[m][r] * ao[m][n2][r] * inv[m][r];
    pa += __shfl_xor(pa, 16, 64);
    pa += __shfl_xor(pa, 32, 64);
    if (l4 == 0) fl[wave*D + n2*16 + l15] = pa;
  }
  __syncthreads();
  for (int c = tid; c < D; c += NT) {
    float s_ = 0.f;
#pragma unroll
    for (int w = 0; w < NW; ++w) s_ += fl[w*D + c];
    pp[((size_t)(b*QB + qb))*1024 + h*D + c] = s_;
  }
}

// ---------- mask denominator ----------
__global__ void denom_kernel(const int* __restrict__ mask, float* __restrict__ denom) {
  int b = blockIdx.x, t = threadIdx.x;
  int acc = 0;
  for (int s = t; s < 1024; s += 256) acc += mask[b*1024 + s];
  for (int o = 32; o; o >>= 1) acc += __shfl_down(acc, o, 64);
  __shared__ int red[4];
  if ((t & 63) == 0) red[t >> 6] = acc;
  __syncthreads();
  if (t == 0) denom[b] = (float)(red[0] + red[1] + red[2] + red[3]);
}

// ---------- pool reduce: sum QB q-block partials, divide by mask denom ----------
__global__ void pool_reduce_kernel(const float* __restrict__ part, const float* __restrict__ denom,
                                   float* __restrict__ out, int QB) {
  int i = blockIdx.x*256 + threadIdx.x;
  int b = i >> 10, c = i & 1023;
  float a = 0.f;
  for (int qb = 0; qb < QB; ++qb) a += part[((size_t)(b*QB + qb))*1024 + c];
  out[i] = a / denom[b];
}

// ---------- O-projection, k-split stage 1 ----------
__global__ void oproj_partial_kernel(const float* __restrict__ pooled,
    const float* __restrict__ W0, const float* __restrict__ W1, const float* __restrict__ W2,
    float* __restrict__ part) {
  int ai = blockIdx.z;
  const float* W = (ai == 0) ? W0 : (ai == 1 ? W1 : W2);
  int ks = blockIdx.y, k0 = ks*128;
  __shared__ float xl[8*128];
  const float* P = pooled + ai*8192;
  for (int i = threadIdx.x; i < 8*128; i += 256) {
    int b = i >> 7, kk = i & 127;
    xl[i] = P[b*1024 + k0 + kk];
  }
  __syncthreads();
  int n = blockIdx.x*256 + threadIdx.x;
  float acc[8] = {};
  for (int kk = 0; kk < 128; ++kk) {
    float w = W[(size_t)(k0+kk)*1024 + n];
#pragma unroll
    for (int b = 0; b < 8; ++b) acc[b] += xl[b*128 + kk] * w;
  }
#pragma unroll
  for (int b = 0; b < 8; ++b) part[(((size_t)ai*8 + ks)*8 + b)*1024 + n] = acc[b];
}

// ---------- O-projection, stage 2 ----------
__global__ void oproj_reduce_kernel(const float* __restrict__ part,
    const float* __restrict__ b0, const float* __restrict__ b1, const float* __restrict__ b2,
    float* __restrict__ fused) {
  int i = blockIdx.x*256 + threadIdx.x;
  int ai = i >> 13, rem = i & 8191;
  int b = rem >> 10, n = rem & 1023;
  const float* bb = (ai == 0) ? b0 : (ai == 1 ? b1 : b2);
  float a = bb[n];
#pragma unroll
  for (int ks = 0; ks < 8; ++ks) a += part[(((size_t)ai*8 + ks)*8 + b)*1024 + n];
  fused[b*3072 + ai*1024 + n] = a;
}

// ---------- small FC: k-split partials, then reduce ----------
__global__ void fc_partial_kernel(const float* __restrict__ X, const float* __restrict__ W,
                                  float* __restrict__ part, int Kin, int Nout, int kchunk) {
  extern __shared__ float xl[];
  int ks = blockIdx.y, k0 = ks*kchunk;
  for (int i = threadIdx.x; i < 8*kchunk; i += 256) {
    int b = i / kchunk, kk = i - b*kchunk;
    xl[i] = X[b*Kin + k0 + kk];
  }
  __syncthreads();
  int n = blockIdx.x*256 + threadIdx.x;
  float acc[8] = {};
  for (int kk = 0; kk < kchunk; ++kk) {
    float w = W[(size_t)(k0+kk)*Nout + n];
#pragma unroll
    for (int b = 0; b < 8; ++b) acc[b] += xl[b*kchunk + kk] * w;
  }
#pragma unroll
  for (int b = 0; b < 8; ++b) part[((size_t)ks*8 + b)*Nout + n] = acc[b];
}

__global__ void fc_reduce_kernel(const float* __restrict__ part, const float* __restrict__ bias,
                                 float* __restrict__ out, int Nout, int KS, int do_relu) {
  int i = blockIdx.x*256 + threadIdx.x;
  int b = i / Nout, n = i - b*Nout;
  float a = bias[n];
  for (int ks = 0; ks < KS; ++ks) a += part[((size_t)ks*8 + b)*Nout + n];
  out[i] = do_relu ? fmaxf(a, 0.f) : a;
}

// ---------- classifier [8,512] @ [512,2] ----------
__global__ void cls_kernel(const float* __restrict__ h2, const float* __restrict__ W,
                           const float* __restrict__ bias, float* __restrict__ out) {
  int t = threadIdx.x;
  int o = t >> 4, sl = t & 15;
  int b = o >> 1, n = o & 1;
  float a = 0.f;
  for (int k = sl; k < 512; k += 16) a += h2[b*512 + k] * W[k*2 + n];
#pragma unroll
  for (int m = 1; m < 16; m <<= 1) a += __shfl_xor(a, m, 64);
  if (sl == 0) out[o] = a + bias[n];
}

extern "C" void kernel_launch(void* const* d_in, const int* in_sizes, int n_in,
                              void* d_out, int out_size, void* d_ws, size_t ws_size,
                              hipStream_t stream) {
  const float* X   = (const float*)d_in[0];
  const int* mask  = (const int*)d_in[1];
  const float* w_[3][8];
  for (int a = 0; a < 3; ++a)
    for (int j = 0; j < 8; ++j)
      w_[a][j] = (const float*)d_in[2 + a*8 + j];
  const float* fus1_w = (const float*)d_in[26];
  const float* fus1_b = (const float*)d_in[27];
  const float* fus2_w = (const float*)d_in[28];
  const float* fus2_b = (const float*)d_in[29];
  const float* cls_w  = (const float*)d_in[30];
  const float* cls_b  = (const float*)d_in[31];

  char* p = (char*)d_ws;
  auto carve = [&](size_t bytes) { char* r = p; p += (bytes + 255) & ~(size_t)255; return r; };
  __bf16* Xb    = (__bf16*)carve((size_t)8192*1024*2);
  __bf16* WTb   = (__bf16*)carve((size_t)3072*1024*2);
  __bf16* QKVb  = (__bf16*)carve((size_t)8192*3072*2);
  __bf16* Vtb   = (__bf16*)carve((size_t)8192*1024*2);
  float* pooledb= (float*)carve(3*8*1024*4);
  float* denomb = (float*)carve(256);
  float* fusedb = (float*)carve(8*3072*4);
  float* partb  = (float*)carve((size_t)24*8*1024*4);
  float* opartb = (float*)carve((size_t)3*8*8*1024*4);
  float* poolpartb = (float*)carve((size_t)8*16*1024*4);
  float* h1b    = (float*)carve(8*1024*4);
  float* h2b    = (float*)carve(8*512*4);
  if ((size_t)(p - (char*)d_ws) > ws_size) return;  // workspace too small: fail loudly

  cvt_bf16_kernel<<<8192, 256, 0, stream>>>(X, Xb, 8192*1024/4);
  denom_kernel<<<8, 256, 0, stream>>>(mask, denomb);

  for (int a = 0; a < 3; ++a) {
    wt_pack_kernel<<<dim3(16,48), 256, 0, stream>>>(w_[a][0], w_[a][2], w_[a][4], WTb);
    if (a == 0) {
      gemm_qkv_kernel<<<dim3(24,64), 256, 0, stream>>>(Xb, WTb, w_[a][1], w_[a][3], w_[a][5],
                                                       QKVb, Vtb, 8, 7);
      attn_kernel<128,16,8,8><<<512, 512, 0, stream>>>(QKVb, Vtb, mask, poolpartb);
      pool_reduce_kernel<<<32, 256, 0, stream>>>(poolpartb, denomb, pooledb + a*8192, 8);
    } else {
      gemm_qkv_kernel<<<dim3(24,64), 256, 0, stream>>>(Xb, WTb, w_[a][1], w_[a][3], w_[a][5],
                                                       QKVb, Vtb, 4, 8);
      attn_kernel<256,16,4,4><<<512, 256, 0, stream>>>(QKVb, Vtb, mask, poolpartb);
      pool_reduce_kernel<<<32, 256, 0, stream>>>(poolpartb, denomb, pooledb + a*8192, 16);
    }
  }

  oproj_partial_kernel<<<dim3(4,8,3), 256, 0, stream>>>(pooledb,
      w_[0][6], w_[1][6], w_[2][6], opartb);
  oproj_reduce_kernel<<<96, 256, 0, stream>>>(opartb,
      w_[0][7], w_[1][7], w_[2][7], fusedb);
  fc_partial_kernel<<<dim3(4,24), 256, 8*128*4, stream>>>(fusedb, fus1_w, partb, 3072, 1024, 128);
  fc_reduce_kernel<<<32, 256, 0, stream>>>(partb, fus1_b, h1b, 1024, 24, 1);
  fc_partial_kernel<<<dim3(2,8), 256, 8*128*4, stream>>>(h1b, fus2_w, partb, 1024, 512, 128);
  fc_reduce_kernel<<<16, 256, 0, stream>>>(partb, fus2_b, h2b, 512, 8, 1);
  cls_kernel<<<1, 256, 0, stream>>>(h2b, cls_w, cls_b, (float*)d_out);
}